// Round 4
// baseline (113.094 us; speedup 1.0000x reference)
//
#include <hip/hip_runtime.h>
#include <hip/hip_bf16.h>
#include <stdint.h>

// out = softmax(x1, -1) @ x2
// x1: [1,16,2048,2048] fp32, x2: [1,16,2048,64] fp32, out: [1,16,2048,64] fp32
//
// R4: barrier-free design. x2 is pre-transposed to bf16 x2t [H][D][S] (4 MiB,
// L2-resident on every XCD). Main kernel uses NO LDS and NO barriers: each
// wave owns 16 output rows, loads A-fragments (x1) straight to registers
// (nontemporal: keep L2 for x2t), exp+bf16 in regs, B-fragments straight from
// L2-resident x2t, MFMA-accumulates. Row-sum in fp32 VALU + shfl reduce.
// Waves free-run -> HBM latency hidden by wave/ILP overlap, no rendezvous.

#define H_  16
#define S_  2048
#define D_  64
#define QT  64    // rows per block (16 per wave, 4 waves)
#define NT  (S_ / 128)

typedef short bf16x8 __attribute__((ext_vector_type(8)));  // 8 bf16 (4 VGPRs)
typedef float f32x4  __attribute__((ext_vector_type(4)));

__device__ __forceinline__ uint16_t f2bf(float f) {  // round-to-nearest-even
  uint32_t u = __builtin_bit_cast(uint32_t, f);
  u += 0x7fffu + ((u >> 16) & 1u);
  return (uint16_t)(u >> 16);
}

// Pre-kernel: x2 [H][S][D] fp32  ->  x2t [H][D][S] bf16 (k-contiguous rows)
__global__ __launch_bounds__(256) void vtrans_kernel(const float* __restrict__ x2,
                                                     uint16_t* __restrict__ x2t) {
  __shared__ float t[D_][64 + 1];  // +1 pad: bank-conflict-free transpose
  const int h  = blockIdx.x >> 5;
  const int k0 = (blockIdx.x & 31) << 6;  // 64-k tile
  const float* src = x2 + ((size_t)h * S_ + k0) * D_;
#pragma unroll
  for (int p = 0; p < 4; ++p) {
    int flat = p * 1024 + threadIdx.x * 4;
    int k = flat >> 6, d = flat & 63;
    float4 v = *(const float4*)(src + (size_t)k * D_ + d);
    t[d + 0][k] = v.x; t[d + 1][k] = v.y; t[d + 2][k] = v.z; t[d + 3][k] = v.w;
  }
  __syncthreads();
  uint16_t* dst = x2t + (size_t)h * D_ * S_ + k0;
#pragma unroll
  for (int p = 0; p < 4; ++p) {
    int flat = p * 1024 + threadIdx.x * 4;
    int d = flat >> 6, k = flat & 63;
    ushort4 o;
    o.x = f2bf(t[d][k + 0]); o.y = f2bf(t[d][k + 1]);
    o.z = f2bf(t[d][k + 2]); o.w = f2bf(t[d][k + 3]);
    *(ushort4*)(dst + (size_t)d * S_ + k) = o;
  }
}

// ---------------- main kernel: no LDS, no barriers ----------------
__global__ __launch_bounds__(256) void smm_direct(const float* __restrict__ x1,
                                                  const uint16_t* __restrict__ x2t,
                                                  float* __restrict__ out) {
  const int tid  = threadIdx.x;
  const int lane = tid & 63;
  const int w    = tid >> 6;                     // wave 0..3
  const int h    = blockIdx.x >> 5;
  const int q0   = (blockIdx.x & 31) * QT + w * 16;  // this wave's 16 rows
  const int arow = lane & 15;
  const int kgrp = lane >> 4;                    // 0..3: k-slice within 32

  // A: lane reads x1[q0+arow][k0 + kgrp*8 .. +8)  (8 consecutive fp32)
  const float* ap = x1 + ((size_t)(h * S_ + q0 + arow)) * S_ + kgrp * 8;
  // B: lane reads x2t[h][c*16+arow][k0 + kgrp*8 .. +8)  (8 consecutive bf16)
  const uint16_t* bbase = x2t + (size_t)h * D_ * S_ + (size_t)arow * S_ + kgrp * 8;
  const uint16_t* b0p = bbase;
  const uint16_t* b1p = bbase + (size_t)16 * S_;
  const uint16_t* b2p = bbase + (size_t)32 * S_;
  const uint16_t* b3p = bbase + (size_t)48 * S_;

  f32x4 acc[4];
#pragma unroll
  for (int c = 0; c < 4; ++c) acc[c] = (f32x4){0.f, 0.f, 0.f, 0.f};
  float rsum = 0.f;   // this lane's partial row-sum (row arow, k-slice kgrp)

#pragma unroll 4
  for (int kt = 0; kt < S_ / 32; ++kt) {
    const int k0 = kt * 32;
    // x1 fragment (nontemporal: stream-once, keep L2 for x2t)
    f32x4 a0 = __builtin_nontemporal_load((const f32x4*)(ap + k0));
    f32x4 a1 = __builtin_nontemporal_load((const f32x4*)(ap + k0 + 4));
    // B fragments from L2-resident x2t
    uint4 b0 = *(const uint4*)(b0p + k0);
    uint4 b1 = *(const uint4*)(b1p + k0);
    uint4 b2 = *(const uint4*)(b2p + k0);
    uint4 b3 = *(const uint4*)(b3p + k0);

    float e0 = __expf(a0[0]), e1 = __expf(a0[1]), e2 = __expf(a0[2]), e3 = __expf(a0[3]);
    float e4 = __expf(a1[0]), e5 = __expf(a1[1]), e6 = __expf(a1[2]), e7 = __expf(a1[3]);
    rsum += ((e0 + e1) + (e2 + e3)) + ((e4 + e5) + (e6 + e7));

    bf16x8 af;
    af[0] = (short)f2bf(e0); af[1] = (short)f2bf(e1);
    af[2] = (short)f2bf(e2); af[3] = (short)f2bf(e3);
    af[4] = (short)f2bf(e4); af[5] = (short)f2bf(e5);
    af[6] = (short)f2bf(e6); af[7] = (short)f2bf(e7);

    acc[0] = __builtin_amdgcn_mfma_f32_16x16x32_bf16(af, __builtin_bit_cast(bf16x8, b0), acc[0], 0, 0, 0);
    acc[1] = __builtin_amdgcn_mfma_f32_16x16x32_bf16(af, __builtin_bit_cast(bf16x8, b1), acc[1], 0, 0, 0);
    acc[2] = __builtin_amdgcn_mfma_f32_16x16x32_bf16(af, __builtin_bit_cast(bf16x8, b2), acc[2], 0, 0, 0);
    acc[3] = __builtin_amdgcn_mfma_f32_16x16x32_bf16(af, __builtin_bit_cast(bf16x8, b3), acc[3], 0, 0, 0);
  }

  // ---- row-sum reduce: combine the 4 k-slices of each row ----
  rsum += __shfl_xor(rsum, 16);
  rsum += __shfl_xor(rsum, 32);   // now every lane has total for row (lane&15)

  // ---- epilogue: normalize, store fp32 ----
  // D layout: col = lane&15, row = (lane>>4)*4 + reg  [verified via refcheck R1]
  float* op = out + ((size_t)(h * S_ + q0)) * D_;
#pragma unroll
  for (int j = 0; j < 4; ++j) {
    int row = (lane >> 4) * 4 + j;
    float s = __shfl(rsum, row);        // lane 'row' holds that row's sum
    float rs = 1.0f / s;
#pragma unroll
    for (int c = 0; c < 4; ++c) {
      float o = acc[c][j] * rs;
      __builtin_nontemporal_store(o, op + (size_t)row * D_ + c * 16 + arow);
    }
  }
}

// ---------------- fallback (tiny workspace): R1 LDS kernel, use_t=0 ----------------
__global__ __launch_bounds__(256) void smm_lds(const float* __restrict__ x1,
                                               const float* __restrict__ x2,
                                               float* __restrict__ out) {
  __shared__ __attribute__((aligned(16))) uint16_t pT[QT][128];
  __shared__ __attribute__((aligned(16))) uint16_t vT[D_][128];

  const int tid  = threadIdx.x;
  const int lane = tid & 63;
  const int w    = tid >> 6;
  const int h    = blockIdx.x >> 5;
  const int q0   = (blockIdx.x & 31) * QT;

  f32x4 acc[4];
  f32x4 accS;
#pragma unroll
  for (int c = 0; c < 4; ++c) acc[c] = (f32x4){0.f, 0.f, 0.f, 0.f};
  accS = (f32x4){0.f, 0.f, 0.f, 0.f};

  bf16x8 ones;
  {
    short v = ((lane & 15) == 0) ? (short)0x3F80 : (short)0;
#pragma unroll
    for (int e = 0; e < 8; ++e) ones[e] = v;
  }

  const float* x1p = x1 + ((size_t)h * S_ + q0) * S_;
  const int prow = tid >> 5;
  const int pk4  = (tid & 31) << 2;
  const int arow = lane & 15;
  const int kgrp = lane >> 4;

  for (int kt = 0; kt < NT; ++kt) {
    __syncthreads();
#pragma unroll
    for (int p = 0; p < 8; ++p) {
      int r = prow + p * 8;
      float4 v = *(const float4*)(x1p + (size_t)r * S_ + kt * 128 + pk4);
      uint32_t lo = (uint32_t)f2bf(__expf(v.x)) | ((uint32_t)f2bf(__expf(v.y)) << 16);
      uint32_t hi = (uint32_t)f2bf(__expf(v.z)) | ((uint32_t)f2bf(__expf(v.w)) << 16);
      int byteoff = (pk4 * 2) ^ ((r & 15) << 4);
      *(uint2*)((char*)(&pT[r][0]) + byteoff) = make_uint2(lo, hi);
    }
    {
      int dd = tid & 63;
      int kg = tid >> 6;
      const float* src = x2 + ((size_t)h * S_ + kt * 128) * D_ + dd;
#pragma unroll
      for (int p = 0; p < 4; ++p) {
        int kb = p * 32 + kg * 8;
        uint16_t tmp[8];
#pragma unroll
        for (int j = 0; j < 8; ++j) tmp[j] = f2bf(src[(size_t)(kb + j) * D_]);
        int byteoff = (kb * 2) ^ ((dd & 15) << 4);
        *(uint4*)((char*)(&vT[dd][0]) + byteoff) = *(uint4*)tmp;
      }
    }
    __syncthreads();
#pragma unroll
    for (int ks = 0; ks < 4; ++ks) {
      int kb = ks * 64 + kgrp * 16;
      int ar = w * 16 + arow;
      bf16x8 a = *(const bf16x8*)((const char*)(&pT[ar][0]) + (kb ^ (arow << 4)));
      accS = __builtin_amdgcn_mfma_f32_16x16x32_bf16(a, ones, accS, 0, 0, 0);
#pragma unroll
      for (int c = 0; c < 4; ++c) {
        int bc = c * 16 + arow;
        bf16x8 b = *(const bf16x8*)((const char*)(&vT[bc][0]) + (kb ^ (arow << 4)));
        acc[c] = __builtin_amdgcn_mfma_f32_16x16x32_bf16(a, b, acc[c], 0, 0, 0);
      }
    }
  }

  float* op = out + ((size_t)h * S_ + q0 + w * 16) * D_;
#pragma unroll
  for (int j = 0; j < 4; ++j) {
    float s = __shfl(accS[j], lane & 48);
    float rs = 1.0f / s;
    int row = (lane >> 4) * 4 + j;
#pragma unroll
    for (int c = 0; c < 4; ++c) {
      op[(size_t)row * D_ + c * 16 + (lane & 15)] = acc[c][j] * rs;
    }
  }
}

extern "C" void kernel_launch(void* const* d_in, const int* in_sizes, int n_in,
                              void* d_out, int out_size, void* d_ws, size_t ws_size,
                              hipStream_t stream) {
  const float* x1 = (const float*)d_in[0];
  const float* x2 = (const float*)d_in[1];
  float* out      = (float*)d_out;
  uint16_t* x2t   = (uint16_t*)d_ws;

  const size_t need = (size_t)H_ * D_ * S_ * sizeof(uint16_t);  // 4 MiB
  if (ws_size >= need) {
    vtrans_kernel<<<dim3(H_ * (S_ / 64)), dim3(256), 0, stream>>>(x2, x2t);
    smm_direct<<<dim3(H_ * (S_ / QT)), dim3(256), 0, stream>>>(x1, x2t, out);
  } else {
    smm_lds<<<dim3(H_ * (S_ / QT)), dim3(256), 0, stream>>>(x1, x2, out);
  }
}

// Round 5
// 80.501 us; speedup vs baseline: 1.4049x; 1.4049x over previous
//
#include <hip/hip_runtime.h>
#include <hip/hip_bf16.h>
#include <stdint.h>

// out = softmax(x1, -1) @ x2
// x1: [1,16,2048,2048] fp32, x2: [1,16,2048,64] fp32, out: [1,16,2048,64] fp32
//
// R5: barrier-free AND coalesced. x2 pre-transposed to bf16 x2t [H][D][S]
// (4 MiB, L2-resident; XCD-swizzle keeps ~512KB/XCD hot). Main kernel has no
// LDS allocation and no __syncthreads: each wave owns 16 rows; per 32-k step
//   - 2 coalesced float4 x1 loads (lane s -> row s>>2, chunk s&3)
//   - exp + pack to bf16 pairs in registers (+ fp32 row-sum partials)
//   - lane-transpose to MFMA A-fragment via 4x ds_bpermute (src lane r*4+kg)
//   - 4 B-fragments straight from x2t (16 rows x 64B = full lines, L2)
//   - 4x mfma_f32_16x16x32_bf16
// Row sums: shfl_xor reduce over the 4 chunk-lanes per row. Normalize in
// epilogue. Waves free-run; latency hidden by TLP/ILP, no rendezvous.

#define H_  16
#define S_  2048
#define D_  64
#define QT  64    // rows per block (16 per wave, 4 waves)
#define NT  (S_ / 128)

typedef short bf16x8 __attribute__((ext_vector_type(8)));  // 8 bf16 (4 VGPRs)
typedef float f32x4  __attribute__((ext_vector_type(4)));

__device__ __forceinline__ uint16_t f2bf(float f) {  // round-to-nearest-even
  uint32_t u = __builtin_bit_cast(uint32_t, f);
  u += 0x7fffu + ((u >> 16) & 1u);
  return (uint16_t)(u >> 16);
}

// Pre-kernel: x2 [H][S][D] fp32  ->  x2t [H][D][S] bf16 (k-contiguous rows)
__global__ __launch_bounds__(256) void vtrans_kernel(const float* __restrict__ x2,
                                                     uint16_t* __restrict__ x2t) {
  __shared__ float t[D_][64 + 1];  // +1 pad: bank-conflict-free transpose
  const int h  = blockIdx.x >> 5;
  const int k0 = (blockIdx.x & 31) << 6;  // 64-k tile
  const float* src = x2 + ((size_t)h * S_ + k0) * D_;
#pragma unroll
  for (int p = 0; p < 4; ++p) {
    int flat = p * 1024 + threadIdx.x * 4;
    int k = flat >> 6, d = flat & 63;
    float4 v = *(const float4*)(src + (size_t)k * D_ + d);
    t[d + 0][k] = v.x; t[d + 1][k] = v.y; t[d + 2][k] = v.z; t[d + 3][k] = v.w;
  }
  __syncthreads();
  uint16_t* dst = x2t + (size_t)h * D_ * S_ + k0;
#pragma unroll
  for (int p = 0; p < 4; ++p) {
    int flat = p * 1024 + threadIdx.x * 4;
    int d = flat >> 6, k = flat & 63;
    ushort4 o;
    o.x = f2bf(t[d][k + 0]); o.y = f2bf(t[d][k + 1]);
    o.z = f2bf(t[d][k + 2]); o.w = f2bf(t[d][k + 3]);
    *(ushort4*)(dst + (size_t)d * S_ + k) = o;
  }
}

// ---------------- main kernel: no LDS, no barriers, coalesced ----------------
__global__ __launch_bounds__(256) void smm_bperm(const float* __restrict__ x1,
                                                 const uint16_t* __restrict__ x2t,
                                                 float* __restrict__ out) {
  // bijective XCD swizzle: 512 blocks = 8 XCDs x 64 contiguous tiles
  const int swz  = (blockIdx.x & 7) * 64 + (blockIdx.x >> 3);
  const int tid  = threadIdx.x;
  const int lane = tid & 63;
  const int w    = tid >> 6;                       // wave 0..3
  const int h    = swz >> 5;
  const int q0   = (swz & 31) * QT + w * 16;       // this wave's 16 rows

  const int r16  = lane & 15;                      // fragment row/col
  const int kg   = lane >> 4;                      // fragment k-group (0..3)
  const int lrow = lane >> 2;                      // load row (0..15)
  const int lchk = lane & 3;                       // load chunk -> k = 8*lchk

  // coalesced x1: lane loads 8 consecutive floats of row lrow at 8*lchk
  const float* ap = x1 + ((size_t)(h * S_ + q0 + lrow)) * S_ + lchk * 8;
  // B: lane reads x2t[h][c*16+r16][k0 + kg*8 ..+8)  (full 64B lines, L2)
  const uint16_t* bbase = x2t + (size_t)h * D_ * S_ + (size_t)r16 * S_ + kg * 8;
  const uint16_t* b0p = bbase;
  const uint16_t* b1p = bbase + (size_t)16 * S_;
  const uint16_t* b2p = bbase + (size_t)32 * S_;
  const uint16_t* b3p = bbase + (size_t)48 * S_;

  // bpermute source lane: fragment (r16, kg) lives in load-lane r16*4+kg
  const int bpidx = (r16 * 4 + kg) << 2;           // byte index

  f32x4 acc[4];
#pragma unroll
  for (int c = 0; c < 4; ++c) acc[c] = (f32x4){0.f, 0.f, 0.f, 0.f};
  float rsum = 0.f;   // partial sum: row lrow, chunk lchk

#pragma unroll 2
  for (int kt = 0; kt < S_ / 32; ++kt) {
    const int k0 = kt * 32;
    f32x4 a0 = *(const f32x4*)(ap + k0);
    f32x4 a1 = *(const f32x4*)(ap + k0 + 4);
    uint4 b0 = *(const uint4*)(b0p + k0);
    uint4 b1 = *(const uint4*)(b1p + k0);
    uint4 b2 = *(const uint4*)(b2p + k0);
    uint4 b3 = *(const uint4*)(b3p + k0);

    float e0 = __expf(a0[0]), e1 = __expf(a0[1]), e2 = __expf(a0[2]), e3 = __expf(a0[3]);
    float e4 = __expf(a1[0]), e5 = __expf(a1[1]), e6 = __expf(a1[2]), e7 = __expf(a1[3]);
    rsum += ((e0 + e1) + (e2 + e3)) + ((e4 + e5) + (e6 + e7));

    uint32_t u0 = (uint32_t)f2bf(e0) | ((uint32_t)f2bf(e1) << 16);
    uint32_t u1 = (uint32_t)f2bf(e2) | ((uint32_t)f2bf(e3) << 16);
    uint32_t u2 = (uint32_t)f2bf(e4) | ((uint32_t)f2bf(e5) << 16);
    uint32_t u3 = (uint32_t)f2bf(e6) | ((uint32_t)f2bf(e7) << 16);

    // lane-transpose: all 4 u32 of fragment (r16, kg) come from lane r16*4+kg
    int f0 = __builtin_amdgcn_ds_bpermute(bpidx, (int)u0);
    int f1 = __builtin_amdgcn_ds_bpermute(bpidx, (int)u1);
    int f2 = __builtin_amdgcn_ds_bpermute(bpidx, (int)u2);
    int f3 = __builtin_amdgcn_ds_bpermute(bpidx, (int)u3);
    uint4 fu = make_uint4((uint32_t)f0, (uint32_t)f1, (uint32_t)f2, (uint32_t)f3);
    bf16x8 af = __builtin_bit_cast(bf16x8, fu);

    acc[0] = __builtin_amdgcn_mfma_f32_16x16x32_bf16(af, __builtin_bit_cast(bf16x8, b0), acc[0], 0, 0, 0);
    acc[1] = __builtin_amdgcn_mfma_f32_16x16x32_bf16(af, __builtin_bit_cast(bf16x8, b1), acc[1], 0, 0, 0);
    acc[2] = __builtin_amdgcn_mfma_f32_16x16x32_bf16(af, __builtin_bit_cast(bf16x8, b2), acc[2], 0, 0, 0);
    acc[3] = __builtin_amdgcn_mfma_f32_16x16x32_bf16(af, __builtin_bit_cast(bf16x8, b3), acc[3], 0, 0, 0);
  }

  // ---- row-sum: combine 4 chunk-lanes per row (lanes 4r..4r+3) ----
  rsum += __shfl_xor(rsum, 1);
  rsum += __shfl_xor(rsum, 2);   // lanes 4r..4r+3 all hold row r's total

  // ---- epilogue: normalize, store fp32 ----
  // D layout: col = lane&15, row = (lane>>4)*4 + reg  [refcheck-verified R1/R4]
  float* op = out + ((size_t)(h * S_ + q0)) * D_;
#pragma unroll
  for (int j = 0; j < 4; ++j) {
    int row = kg * 4 + j;
    float s = __shfl(rsum, row * 4);    // lane 4*row holds row's sum
    float rs = 1.0f / s;
    float o = acc[0][j] * rs;
    __builtin_nontemporal_store(o, op + (size_t)row * D_ + 0 * 16 + r16);
    o = acc[1][j] * rs;
    __builtin_nontemporal_store(o, op + (size_t)row * D_ + 1 * 16 + r16);
    o = acc[2][j] * rs;
    __builtin_nontemporal_store(o, op + (size_t)row * D_ + 2 * 16 + r16);
    o = acc[3][j] * rs;
    __builtin_nontemporal_store(o, op + (size_t)row * D_ + 3 * 16 + r16);
  }
}

// ---------------- fallback (tiny workspace): R1 LDS kernel ----------------
__global__ __launch_bounds__(256) void smm_lds(const float* __restrict__ x1,
                                               const float* __restrict__ x2,
                                               float* __restrict__ out) {
  __shared__ __attribute__((aligned(16))) uint16_t pT[QT][128];
  __shared__ __attribute__((aligned(16))) uint16_t vT[D_][128];

  const int tid  = threadIdx.x;
  const int lane = tid & 63;
  const int w    = tid >> 6;
  const int h    = blockIdx.x >> 5;
  const int q0   = (blockIdx.x & 31) * QT;

  f32x4 acc[4];
  f32x4 accS;
#pragma unroll
  for (int c = 0; c < 4; ++c) acc[c] = (f32x4){0.f, 0.f, 0.f, 0.f};
  accS = (f32x4){0.f, 0.f, 0.f, 0.f};

  bf16x8 ones;
  {
    short v = ((lane & 15) == 0) ? (short)0x3F80 : (short)0;
#pragma unroll
    for (int e = 0; e < 8; ++e) ones[e] = v;
  }

  const float* x1p = x1 + ((size_t)h * S_ + q0) * S_;
  const int prow = tid >> 5;
  const int pk4  = (tid & 31) << 2;
  const int arow = lane & 15;
  const int kgrp = lane >> 4;

  for (int kt = 0; kt < NT; ++kt) {
    __syncthreads();
#pragma unroll
    for (int p = 0; p < 8; ++p) {
      int r = prow + p * 8;
      float4 v = *(const float4*)(x1p + (size_t)r * S_ + kt * 128 + pk4);
      uint32_t lo = (uint32_t)f2bf(__expf(v.x)) | ((uint32_t)f2bf(__expf(v.y)) << 16);
      uint32_t hi = (uint32_t)f2bf(__expf(v.z)) | ((uint32_t)f2bf(__expf(v.w)) << 16);
      int byteoff = (pk4 * 2) ^ ((r & 15) << 4);
      *(uint2*)((char*)(&pT[r][0]) + byteoff) = make_uint2(lo, hi);
    }
    {
      int dd = tid & 63;
      int kgq = tid >> 6;
      const float* src = x2 + ((size_t)h * S_ + kt * 128) * D_ + dd;
#pragma unroll
      for (int p = 0; p < 4; ++p) {
        int kb = p * 32 + kgq * 8;
        uint16_t tmp[8];
#pragma unroll
        for (int j = 0; j < 8; ++j) tmp[j] = f2bf(src[(size_t)(kb + j) * D_]);
        int byteoff = (kb * 2) ^ ((dd & 15) << 4);
        *(uint4*)((char*)(&vT[dd][0]) + byteoff) = *(uint4*)tmp;
      }
    }
    __syncthreads();
#pragma unroll
    for (int ks = 0; ks < 4; ++ks) {
      int kb = ks * 64 + kgrp * 16;
      int ar = w * 16 + arow;
      bf16x8 a = *(const bf16x8*)((const char*)(&pT[ar][0]) + (kb ^ (arow << 4)));
      accS = __builtin_amdgcn_mfma_f32_16x16x32_bf16(a, ones, accS, 0, 0, 0);
#pragma unroll
      for (int c = 0; c < 4; ++c) {
        int bc = c * 16 + arow;
        bf16x8 b = *(const bf16x8*)((const char*)(&vT[bc][0]) + (kb ^ (arow << 4)));
        acc[c] = __builtin_amdgcn_mfma_f32_16x16x32_bf16(a, b, acc[c], 0, 0, 0);
      }
    }
  }

  float* op = out + ((size_t)h * S_ + q0 + w * 16) * D_;
#pragma unroll
  for (int j = 0; j < 4; ++j) {
    float s = __shfl(accS[j], lane & 48);
    float rs = 1.0f / s;
    int row = (lane >> 4) * 4 + j;
#pragma unroll
    for (int c = 0; c < 4; ++c) {
      op[(size_t)row * D_ + c * 16 + (lane & 15)] = acc[c][j] * rs;
    }
  }
}

extern "C" void kernel_launch(void* const* d_in, const int* in_sizes, int n_in,
                              void* d_out, int out_size, void* d_ws, size_t ws_size,
                              hipStream_t stream) {
  const float* x1 = (const float*)d_in[0];
  const float* x2 = (const float*)d_in[1];
  float* out      = (float*)d_out;
  uint16_t* x2t   = (uint16_t*)d_ws;

  const size_t need = (size_t)H_ * D_ * S_ * sizeof(uint16_t);  // 4 MiB
  if (ws_size >= need) {
    vtrans_kernel<<<dim3(H_ * (S_ / 64)), dim3(256), 0, stream>>>(x2, x2t);
    smm_bperm<<<dim3(H_ * (S_ / QT)), dim3(256), 0, stream>>>(x1, x2t, out);
  } else {
    smm_lds<<<dim3(H_ * (S_ / QT)), dim3(256), 0, stream>>>(x1, x2, out);
  }
}